// Round 4
// baseline (529.026 us; speedup 1.0000x reference)
//
#include <hip/hip_runtime.h>

// Problem constants (fixed by the reference setup)
#define Bd 4
#define Cd 64
#define Hd 512
#define Wd 512
#define HWp (Hd * Wd)        // 262144 = 2^18 pixels per image
#define NSd 2048
#define NLd 1000

// ===========================================================================
// FAST PATH (counting sort, no atomics in the hot loop)
// Workspace layout (element counts):
//   cnt    [B*NL]   int    label counts per image
//   start  [B*NL]   int    exclusive prefix (run starts)
//   cursor [B*NL]   int    scatter cursors (init = start)
//   perm   [B*HW]   int    pixel indices grouped by label
//   means  [B*NL*C] float  per-label per-channel means, channel-minor
// ===========================================================================
#define OFF_CNT    0
#define OFF_START  (Bd * NLd)
#define OFF_CURSOR (2 * Bd * NLd)
#define OFF_PERM   (3 * Bd * NLd)
#define OFF_MEANS  (3 * Bd * NLd + Bd * HWp)
#define WS_FAST_ELEMS (3 * Bd * NLd + Bd * HWp + Bd * NLd * Cd)

__global__ __launch_bounds__(256)
void hist_kernel(const int* __restrict__ lab, int* __restrict__ cnt) {
    __shared__ unsigned h[NLd];
    const int tid   = threadIdx.x;
    const int chunk = blockIdx.x;
    const int b     = blockIdx.y;

    for (int l = tid; l < NLd; l += 256) h[l] = 0u;
    __syncthreads();

    const int4* __restrict__ lp = (const int4*)lab + (size_t)b * (HWp / 4);
    const int nvec = HWp / 4 / 4;        // 16384
    const int v0 = chunk * nvec, v1 = v0 + nvec;
    for (int v = v0 + tid; v < v1; v += 256) {
        int4 lv = lp[v];
        atomicAdd(&h[lv.x & (1023)], 1u);   // defensive mask (labels < 1000)
        atomicAdd(&h[lv.y & (1023)], 1u);
        atomicAdd(&h[lv.z & (1023)], 1u);
        atomicAdd(&h[lv.w & (1023)], 1u);
    }
    __syncthreads();

    for (int l = tid; l < NLd; l += 256)
        atomicAdd(&cnt[b * NLd + l], (int)h[l]);
}

// Defensive: mask must stay inside h[NLd]; use min() not & since 1023>999.
// (Replaced above uses of &1023 with min via macro to be strictly safe.)

__global__ __launch_bounds__(1024)
void scan_kernel(const int* __restrict__ cnt, int* __restrict__ start,
                 int* __restrict__ cursor) {
    __shared__ int buf[1024];
    const int tid = threadIdx.x;
    const int b   = blockIdx.x;

    int v = (tid < NLd) ? cnt[b * NLd + tid] : 0;
    buf[tid] = v;
    __syncthreads();
    for (int off = 1; off < 1024; off <<= 1) {
        int t = (tid >= off) ? buf[tid - off] : 0;
        __syncthreads();
        buf[tid] += t;
        __syncthreads();
    }
    if (tid < NLd) {
        int excl = buf[tid] - v;
        start[b * NLd + tid]  = excl;
        cursor[b * NLd + tid] = excl;
    }
}

__global__ __launch_bounds__(256)
void scatter_kernel(const int* __restrict__ lab, int* __restrict__ cursor,
                    int* __restrict__ perm) {
    const int t = blockIdx.x * 256 + threadIdx.x;   // 0 .. B*HW-1
    const int b = t >> 18;                          // HW = 2^18
    int l = lab[t];
    l = (l < 0) ? 0 : (l >= NLd ? NLd - 1 : l);     // defensive clamp
    int pos = atomicAdd(&cursor[b * NLd + l], 1);
    pos = (pos < 0) ? 0 : (pos >= HWp ? HWp - 1 : pos);  // defensive clamp
    perm[(b << 18) + pos] = t & (HWp - 1);
}

__global__ __launch_bounds__(256)
void sum_kernel(const float* __restrict__ x, const int* __restrict__ cnt,
                const int* __restrict__ start, const int* __restrict__ perm,
                float* __restrict__ means) {
    const int bid = blockIdx.x;
    // XCD-aware mapping: all 250 blocks of one (b,c) plane land on one XCD
    // so the plane (1MB) + perm image (1MB) stay L2-resident.
    const int xcd         = bid & 7;
    const int idx         = bid >> 3;        // 0..7999
    const int plane_local = idx / 250;       // 0..31
    const int chunk       = idx % 250;       // 0..249
    const int plane       = plane_local * 8 + xcd;   // 0..255
    const int b           = plane >> 6;
    const int c           = plane & 63;

    const int w    = threadIdx.x >> 6;       // wave 0..3
    const int lane = threadIdx.x & 63;
    const int l    = chunk * 4 + w;          // 0..999

    int n = cnt[b * NLd + l];
    int s = start[b * NLd + l];
    // defensive clamps: keep all reads inside this image's perm slice
    if (s < 0) s = 0;
    if (s > HWp) s = HWp;
    if (n < 0) n = 0;
    if (n > HWp - s) n = HWp - s;

    const float* __restrict__ xp = x + ((size_t)plane << 18);
    const int*   __restrict__ pp = perm + ((size_t)b << 18) + s;

    float acc = 0.0f;
    for (int i = lane; i < n; i += 64)
        acc += xp[pp[i] & (HWp - 1)];

    #pragma unroll
    for (int off = 32; off > 0; off >>= 1)
        acc += __shfl_xor(acc, off, 64);

    if (lane == 0)
        means[((size_t)(b * NLd + l) << 6) + c] = acc / (float)(n > 0 ? n : 1);
}

__global__ __launch_bounds__(256)
void gather_kernel(const float* __restrict__ means,
                   const int* __restrict__ edges,
                   const float* __restrict__ ew,
                   float* __restrict__ out) {
    const int t  = blockIdx.x * 256 + threadIdx.x;   // 0 .. B*NS*C-1
    const int bs = t >> 6;                           // b*NS + s
    const int c  = t & 63;
    const int b  = bs >> 11;                         // NS = 2048

    int la = edges[bs * 2 + 0];
    int lb = edges[bs * 2 + 1];
    la = (la < 0) ? 0 : (la >= NLd ? NLd - 1 : la);
    lb = (lb < 0) ? 0 : (lb >= NLd ? NLd - 1 : lb);

    out[t] = means[((size_t)(b * NLd + la) << 6) + c];
    out[(size_t)Bd * NSd * Cd + t] = means[((size_t)(b * NLd + lb) << 6) + c];
    if (t < Bd * NSd)
        out[2 * (size_t)Bd * NSd * Cd + t] = ew[t];
}

// ===========================================================================
// FALLBACK PATH (R1 design: LDS-atomic histogram sums; needs only ~1 MB ws)
//   sums   [B*C*NL] float
//   counts [B*NL]   float
// ===========================================================================
#define WS_FB_ELEMS (Bd * Cd * NLd + Bd * NLd)

__global__ __launch_bounds__(256)
void fb_sums_kernel(const float* __restrict__ x, const int* __restrict__ lab,
                    float* __restrict__ sums) {
    __shared__ float lsum[NLd];
    const int tid   = threadIdx.x;
    const int chunk = blockIdx.x;
    const int c     = blockIdx.y;
    const int b     = blockIdx.z;

    for (int l = tid; l < NLd; l += 256) lsum[l] = 0.0f;
    __syncthreads();

    const float4* __restrict__ xp =
        (const float4*)x + (size_t)(b * Cd + c) * (HWp / 4);
    const int4* __restrict__ lp = (const int4*)lab + (size_t)b * (HWp / 4);

    const int nvec = HWp / 4 / 4;
    const int v0 = chunk * nvec, v1 = v0 + nvec;
    for (int v = v0 + tid; v < v1; v += 256) {
        float4 xv = xp[v];
        int4   lv = lp[v];
        atomicAdd(&lsum[min(lv.x, NLd - 1)], xv.x);
        atomicAdd(&lsum[min(lv.y, NLd - 1)], xv.y);
        atomicAdd(&lsum[min(lv.z, NLd - 1)], xv.z);
        atomicAdd(&lsum[min(lv.w, NLd - 1)], xv.w);
    }
    __syncthreads();

    float* __restrict__ dst = sums + (size_t)(b * Cd + c) * NLd;
    for (int l = tid; l < NLd; l += 256)
        atomicAdd(&dst[l], lsum[l]);
}

__global__ __launch_bounds__(256)
void fb_counts_kernel(const int* __restrict__ lab, float* __restrict__ counts) {
    __shared__ unsigned lcnt[NLd];
    const int tid   = threadIdx.x;
    const int chunk = blockIdx.x;
    const int b     = blockIdx.y;

    for (int l = tid; l < NLd; l += 256) lcnt[l] = 0u;
    __syncthreads();

    const int4* __restrict__ lp = (const int4*)lab + (size_t)b * (HWp / 4);
    const int nvec = HWp / 4 / 4;
    const int v0 = chunk * nvec, v1 = v0 + nvec;
    for (int v = v0 + tid; v < v1; v += 256) {
        int4 lv = lp[v];
        atomicAdd(&lcnt[min(lv.x, NLd - 1)], 1u);
        atomicAdd(&lcnt[min(lv.y, NLd - 1)], 1u);
        atomicAdd(&lcnt[min(lv.z, NLd - 1)], 1u);
        atomicAdd(&lcnt[min(lv.w, NLd - 1)], 1u);
    }
    __syncthreads();

    float* __restrict__ dst = counts + (size_t)b * NLd;
    for (int l = tid; l < NLd; l += 256)
        atomicAdd(&dst[l], (float)lcnt[l]);
}

__global__ __launch_bounds__(256)
void fb_gather_kernel(const float* __restrict__ sums,
                      const float* __restrict__ counts,
                      const int* __restrict__ edges,
                      const float* __restrict__ ew,
                      float* __restrict__ out) {
    const int t  = blockIdx.x * 256 + threadIdx.x;
    const int bs = t >> 6;
    const int c  = t & 63;
    const int b  = bs >> 11;

    int la = edges[bs * 2 + 0];
    int lb = edges[bs * 2 + 1];
    la = (la < 0) ? 0 : (la >= NLd ? NLd - 1 : la);
    lb = (lb < 0) ? 0 : (lb >= NLd ? NLd - 1 : lb);

    const float ca = fmaxf(counts[b * NLd + la], 1.0f);
    const float cb = fmaxf(counts[b * NLd + lb], 1.0f);

    const size_t plane = (size_t)(b * Cd + c) * NLd;
    out[t] = sums[plane + la] / ca;
    out[(size_t)Bd * NSd * Cd + t] = sums[plane + lb] / cb;
    if (t < Bd * NSd)
        out[2 * (size_t)Bd * NSd * Cd + t] = ew[t];
}

extern "C" void kernel_launch(void* const* d_in, const int* in_sizes, int n_in,
                              void* d_out, int out_size, void* d_ws, size_t ws_size,
                              hipStream_t stream) {
    const float* x     = (const float*)d_in[0];   // [B,C,H,W] f32
    const int*   lab   = (const int*)d_in[1];     // [B,1,H,W] i32
    const int*   edges = (const int*)d_in[2];     // [B,NS,2] i32
    const float* ew    = (const float*)d_in[3];   // [B,NS] f32
    float*       out   = (float*)d_out;

    const int n_gather = Bd * NSd * Cd;   // 524288

    if (ws_size >= (size_t)WS_FAST_ELEMS * sizeof(int)) {
        // ---- fast path: counting sort ----
        int*   wsi    = (int*)d_ws;
        int*   cnt    = wsi + OFF_CNT;
        int*   start  = wsi + OFF_START;
        int*   cursor = wsi + OFF_CURSOR;
        int*   perm   = wsi + OFF_PERM;
        float* means  = (float*)(wsi + OFF_MEANS);

        hipMemsetAsync(cnt, 0, (size_t)Bd * NLd * sizeof(int), stream);

        hist_kernel<<<dim3(4, Bd), 256, 0, stream>>>(lab, cnt);
        scan_kernel<<<Bd, 1024, 0, stream>>>(cnt, start, cursor);
        scatter_kernel<<<(Bd * HWp) / 256, 256, 0, stream>>>(lab, cursor, perm);
        sum_kernel<<<64000, 256, 0, stream>>>(x, cnt, start, perm, means);
        gather_kernel<<<n_gather / 256, 256, 0, stream>>>(means, edges, ew, out);
    } else {
        // ---- fallback: R1 atomic path (needs ~1 MB ws; known-good 371 us) ----
        float* sums   = (float*)d_ws;                  // [B,C,NL]
        float* counts = sums + (size_t)Bd * Cd * NLd;  // [B,NL]

        hipMemsetAsync(d_ws, 0, (size_t)WS_FB_ELEMS * sizeof(float), stream);

        fb_sums_kernel<<<dim3(4, Cd, Bd), 256, 0, stream>>>(x, lab, sums);
        fb_counts_kernel<<<dim3(4, Bd), 256, 0, stream>>>(lab, counts);
        fb_gather_kernel<<<n_gather / 256, 256, 0, stream>>>(sums, counts, edges, ew, out);
    }
}

// Round 5
// 352.954 us; speedup vs baseline: 1.4989x; 1.4989x over previous
//
#include <hip/hip_runtime.h>

// Problem constants (fixed by the reference setup)
#define Bd 4
#define Cd 64
#define HWp 262144           // 512*512 = 2^18 pixels per image
#define NSd 2048
#define NLd 1000

// ===========================================================================
// FAST PATH: counting sort + pixel-major bf16 transpose + coalesced label sums
// ws layout (int-element offsets):
//   cnt    [B*NL]        int
//   start  [B*NL]        int
//   cursor [B*NL]        int
//   perm   [B*HW]        int      pixel ids grouped by label
//   means  [B*NL*C]      float    channel-minor
//   xt     [HW*C/2]      u32      ONE image, pixel-major bf16 pairs (reused)
// ===========================================================================
#define OFF_CNT    0
#define OFF_START  (Bd * NLd)
#define OFF_CURSOR (2 * Bd * NLd)
#define OFF_PERM   (3 * Bd * NLd)
#define OFF_MEANS  (3 * Bd * NLd + Bd * HWp)
#define OFF_XT     (OFF_MEANS + Bd * NLd * Cd)
#define WS_ELEMS   (OFF_XT + HWp * Cd / 2)

__device__ __forceinline__ unsigned short f2bf(float f) {
    unsigned u = __float_as_uint(f);
    u += 0x7FFFu + ((u >> 16) & 1u);          // round-to-nearest-even
    return (unsigned short)(u >> 16);
}
__device__ __forceinline__ float bflo(unsigned u) { return __uint_as_float(u << 16); }
__device__ __forceinline__ float bfhi(unsigned u) { return __uint_as_float(u & 0xFFFF0000u); }

__global__ __launch_bounds__(256)
void hist_kernel(const int* __restrict__ lab, int* __restrict__ cnt) {
    __shared__ unsigned h[NLd];
    const int tid   = threadIdx.x;
    const int chunk = blockIdx.x;
    const int b     = blockIdx.y;

    for (int l = tid; l < NLd; l += 256) h[l] = 0u;
    __syncthreads();

    const int4* __restrict__ lp = (const int4*)lab + (size_t)b * (HWp / 4);
    const int nvec = HWp / 16;               // 16384 int4 per chunk
    const int v0 = chunk * nvec, v1 = v0 + nvec;
    for (int v = v0 + tid; v < v1; v += 256) {
        int4 lv = lp[v];
        atomicAdd(&h[min(lv.x, NLd - 1)], 1u);
        atomicAdd(&h[min(lv.y, NLd - 1)], 1u);
        atomicAdd(&h[min(lv.z, NLd - 1)], 1u);
        atomicAdd(&h[min(lv.w, NLd - 1)], 1u);
    }
    __syncthreads();

    for (int l = tid; l < NLd; l += 256)
        atomicAdd(&cnt[b * NLd + l], (int)h[l]);
}

__global__ __launch_bounds__(1024)
void scan_kernel(const int* __restrict__ cnt, int* __restrict__ start,
                 int* __restrict__ cursor) {
    __shared__ int buf[1024];
    const int tid = threadIdx.x;
    const int b   = blockIdx.x;

    int v = (tid < NLd) ? cnt[b * NLd + tid] : 0;
    buf[tid] = v;
    __syncthreads();
    for (int off = 1; off < 1024; off <<= 1) {
        int t = (tid >= off) ? buf[tid - off] : 0;
        __syncthreads();
        buf[tid] += t;
        __syncthreads();
    }
    if (tid < NLd) {
        int excl = buf[tid] - v;
        start[b * NLd + tid]  = excl;
        cursor[b * NLd + tid] = excl;
    }
}

__global__ __launch_bounds__(256)
void scatter_kernel(const int* __restrict__ lab, int* __restrict__ cursor,
                    int* __restrict__ perm) {
    const int t = blockIdx.x * 256 + threadIdx.x;   // 0 .. B*HW-1
    const int b = t >> 18;
    int l = lab[t];
    l = (l < 0) ? 0 : (l >= NLd ? NLd - 1 : l);
    int pos = atomicAdd(&cursor[b * NLd + l], 1);
    pos = (pos < 0) ? 0 : (pos >= HWp ? HWp - 1 : pos);
    perm[(b << 18) + pos] = t & (HWp - 1);
}

// ---------------------------------------------------------------------------
// Transpose one image: x[b][C][HW] f32 -> xt[HW][C] bf16 (packed u32 pairs).
// 64x64 tile in LDS ([64][65] f32: (p+c)%32 banks -> 2-way = free).
// grid = HW/64 = 4096, block = 256.
// ---------------------------------------------------------------------------
__global__ __launch_bounds__(256)
void transpose_kernel(const float* __restrict__ x, unsigned* __restrict__ xt, int b) {
    __shared__ float lds[64 * 65];
    const int tid = threadIdx.x;
    const int p0  = blockIdx.x * 64;
    const float* __restrict__ xb = x + ((size_t)b * Cd << 18);

    // phase 1: float4 reads along pixels, store [p][c] into LDS
    #pragma unroll
    for (int it = 0; it < 4; ++it) {
        const int c = it * 16 + (tid >> 4);
        const int j = tid & 15;
        float4 v = *(const float4*)(xb + ((size_t)c << 18) + p0 + 4 * j);
        lds[(4 * j + 0) * 65 + c] = v.x;
        lds[(4 * j + 1) * 65 + c] = v.y;
        lds[(4 * j + 2) * 65 + c] = v.z;
        lds[(4 * j + 3) * 65 + c] = v.w;
    }
    __syncthreads();

    // phase 2: pack 2 channels -> u32 bf16 pair, coalesced pixel-major store
    #pragma unroll
    for (int it = 0; it < 8; ++it) {
        const int p  = it * 8 + (tid >> 5);
        const int cp = tid & 31;
        float lo = lds[p * 65 + 2 * cp];
        float hi = lds[p * 65 + 2 * cp + 1];
        unsigned packed = ((unsigned)f2bf(hi) << 16) | (unsigned)f2bf(lo);
        xt[(size_t)(p0 + p) * 32 + cp] = packed;
    }
}

// ---------------------------------------------------------------------------
// Per-image label sums. grid = 250 blocks x 256 thr; wave w handles label
// l = bid*4+w. Lanes: half = lane>>5 picks pixel of a pair, cp = lane&31 is
// the channel pair. Each pixel read = one u32 (2 channels) -> the wave pulls
// 2 pixels x 128B contiguous per instruction. perm slice staged in LDS.
// ---------------------------------------------------------------------------
__global__ __launch_bounds__(256)
void sum_kernel(const unsigned* __restrict__ xt, const int* __restrict__ cnt,
                const int* __restrict__ start, const int* __restrict__ perm,
                float* __restrict__ means, int b) {
    __shared__ int sperm[3072];
    const int tid  = threadIdx.x;
    const int l0   = blockIdx.x * 4;
    const int lane = tid & 63;
    const int w    = tid >> 6;
    const int l    = l0 + w;

    // stage the contiguous perm range of this block's 4 labels
    int sB = start[b * NLd + l0];
    const int lastI = b * NLd + l0 + 3;
    int sE = start[lastI] + cnt[lastI];
    if (sB < 0) sB = 0; if (sB > HWp) sB = HWp;
    int tot = sE - sB;
    if (tot < 0) tot = 0;
    if (tot > HWp - sB) tot = HWp - sB;
    const int stg = tot > 3072 ? 3072 : tot;

    const int* __restrict__ gp = perm + ((size_t)b << 18);
    for (int t = tid; t < stg; t += 256) sperm[t] = gp[sB + t];
    __syncthreads();

    int n = cnt[b * NLd + l];
    int s = start[b * NLd + l];
    if (s < sB) s = sB; if (s > HWp) s = HWp;
    if (n < 0) n = 0;
    if (n > HWp - s) n = HWp - s;
    const int off = s - sB;

    const int half = lane >> 5;
    const int cp   = lane & 31;

    float s0a = 0, s1a = 0, s0b = 0, s1b = 0, s0c = 0, s1c = 0, s0d = 0, s1d = 0;
    float s0e = 0, s1e = 0, s0f = 0, s1f = 0, s0g = 0, s1g = 0, s0h = 0, s1h = 0;

    int i = 0;
    for (; i + 16 <= n; i += 16) {
        int pA, pB, pC, pD, pE, pF, pG, pH;
        if (off + i + 16 <= stg) {
            const int base = off + i + half;
            pA = sperm[base +  0]; pB = sperm[base +  2];
            pC = sperm[base +  4]; pD = sperm[base +  6];
            pE = sperm[base +  8]; pF = sperm[base + 10];
            pG = sperm[base + 12]; pH = sperm[base + 14];
        } else {
            const int base = s + i + half;
            pA = gp[base +  0]; pB = gp[base +  2];
            pC = gp[base +  4]; pD = gp[base +  6];
            pE = gp[base +  8]; pF = gp[base + 10];
            pG = gp[base + 12]; pH = gp[base + 14];
        }
        unsigned uA = xt[(size_t)pA * 32 + cp];
        unsigned uB = xt[(size_t)pB * 32 + cp];
        unsigned uC = xt[(size_t)pC * 32 + cp];
        unsigned uD = xt[(size_t)pD * 32 + cp];
        unsigned uE = xt[(size_t)pE * 32 + cp];
        unsigned uF = xt[(size_t)pF * 32 + cp];
        unsigned uG = xt[(size_t)pG * 32 + cp];
        unsigned uH = xt[(size_t)pH * 32 + cp];
        s0a += bflo(uA); s1a += bfhi(uA);
        s0b += bflo(uB); s1b += bfhi(uB);
        s0c += bflo(uC); s1c += bfhi(uC);
        s0d += bflo(uD); s1d += bfhi(uD);
        s0e += bflo(uE); s1e += bfhi(uE);
        s0f += bflo(uF); s1f += bfhi(uF);
        s0g += bflo(uG); s1g += bfhi(uG);
        s0h += bflo(uH); s1h += bfhi(uH);
    }
    for (; i + 2 <= n; i += 2) {
        const int idx = off + i + half;
        const int p = (idx < stg) ? sperm[idx] : gp[s + i + half];
        unsigned u = xt[(size_t)p * 32 + cp];
        s0a += bflo(u); s1a += bfhi(u);
    }
    if (i < n && half == 0) {
        const int idx = off + i;
        const int p = (idx < stg) ? sperm[idx] : gp[s + i];
        unsigned u = xt[(size_t)p * 32 + cp];
        s0a += bflo(u); s1a += bfhi(u);
    }

    float a0 = ((s0a + s0b) + (s0c + s0d)) + ((s0e + s0f) + (s0g + s0h));
    float a1 = ((s1a + s1b) + (s1c + s1d)) + ((s1e + s1f) + (s1g + s1h));
    a0 += __shfl_xor(a0, 32, 64);
    a1 += __shfl_xor(a1, 32, 64);

    if (half == 0) {
        const float inv = 1.0f / (float)(n > 0 ? n : 1);
        float2 o; o.x = a0 * inv; o.y = a1 * inv;
        *(float2*)(means + (((size_t)(b * NLd + l)) << 6) + 2 * cp) = o;
    }
}

__global__ __launch_bounds__(256)
void gather_kernel(const float* __restrict__ means,
                   const int* __restrict__ edges,
                   const float* __restrict__ ew,
                   float* __restrict__ out) {
    const int t  = blockIdx.x * 256 + threadIdx.x;   // 0 .. B*NS*C-1
    const int bs = t >> 6;                           // b*NS + s
    const int c  = t & 63;
    const int b  = bs >> 11;                         // NS = 2048

    int la = edges[bs * 2 + 0];
    int lb = edges[bs * 2 + 1];
    la = (la < 0) ? 0 : (la >= NLd ? NLd - 1 : la);
    lb = (lb < 0) ? 0 : (lb >= NLd ? NLd - 1 : lb);

    out[t] = means[((size_t)(b * NLd + la) << 6) + c];
    out[(size_t)Bd * NSd * Cd + t] = means[((size_t)(b * NLd + lb) << 6) + c];
    if (t < Bd * NSd)
        out[2 * (size_t)Bd * NSd * Cd + t] = ew[t];
}

// ===========================================================================
// FALLBACK PATH (R1 design, known-good 371 us; needs ~1 MB ws)
// ===========================================================================
#define WS_FB_ELEMS (Bd * Cd * NLd + Bd * NLd)

__global__ __launch_bounds__(256)
void fb_sums_kernel(const float* __restrict__ x, const int* __restrict__ lab,
                    float* __restrict__ sums) {
    __shared__ float lsum[NLd];
    const int tid   = threadIdx.x;
    const int chunk = blockIdx.x;
    const int c     = blockIdx.y;
    const int b     = blockIdx.z;

    for (int l = tid; l < NLd; l += 256) lsum[l] = 0.0f;
    __syncthreads();

    const float4* __restrict__ xp =
        (const float4*)x + (size_t)(b * Cd + c) * (HWp / 4);
    const int4* __restrict__ lp = (const int4*)lab + (size_t)b * (HWp / 4);

    const int nvec = HWp / 16;
    const int v0 = chunk * nvec, v1 = v0 + nvec;
    for (int v = v0 + tid; v < v1; v += 256) {
        float4 xv = xp[v];
        int4   lv = lp[v];
        atomicAdd(&lsum[min(lv.x, NLd - 1)], xv.x);
        atomicAdd(&lsum[min(lv.y, NLd - 1)], xv.y);
        atomicAdd(&lsum[min(lv.z, NLd - 1)], xv.z);
        atomicAdd(&lsum[min(lv.w, NLd - 1)], xv.w);
    }
    __syncthreads();

    float* __restrict__ dst = sums + (size_t)(b * Cd + c) * NLd;
    for (int l = tid; l < NLd; l += 256)
        atomicAdd(&dst[l], lsum[l]);
}

__global__ __launch_bounds__(256)
void fb_counts_kernel(const int* __restrict__ lab, float* __restrict__ counts) {
    __shared__ unsigned lcnt[NLd];
    const int tid   = threadIdx.x;
    const int chunk = blockIdx.x;
    const int b     = blockIdx.y;

    for (int l = tid; l < NLd; l += 256) lcnt[l] = 0u;
    __syncthreads();

    const int4* __restrict__ lp = (const int4*)lab + (size_t)b * (HWp / 4);
    const int nvec = HWp / 16;
    const int v0 = chunk * nvec, v1 = v0 + nvec;
    for (int v = v0 + tid; v < v1; v += 256) {
        int4 lv = lp[v];
        atomicAdd(&lcnt[min(lv.x, NLd - 1)], 1u);
        atomicAdd(&lcnt[min(lv.y, NLd - 1)], 1u);
        atomicAdd(&lcnt[min(lv.z, NLd - 1)], 1u);
        atomicAdd(&lcnt[min(lv.w, NLd - 1)], 1u);
    }
    __syncthreads();

    float* __restrict__ dst = counts + (size_t)b * NLd;
    for (int l = tid; l < NLd; l += 256)
        atomicAdd(&dst[l], (float)lcnt[l]);
}

__global__ __launch_bounds__(256)
void fb_gather_kernel(const float* __restrict__ sums,
                      const float* __restrict__ counts,
                      const int* __restrict__ edges,
                      const float* __restrict__ ew,
                      float* __restrict__ out) {
    const int t  = blockIdx.x * 256 + threadIdx.x;
    const int bs = t >> 6;
    const int c  = t & 63;
    const int b  = bs >> 11;

    int la = edges[bs * 2 + 0];
    int lb = edges[bs * 2 + 1];
    la = (la < 0) ? 0 : (la >= NLd ? NLd - 1 : la);
    lb = (lb < 0) ? 0 : (lb >= NLd ? NLd - 1 : lb);

    const float ca = fmaxf(counts[b * NLd + la], 1.0f);
    const float cb = fmaxf(counts[b * NLd + lb], 1.0f);

    const size_t plane = (size_t)(b * Cd + c) * NLd;
    out[t] = sums[plane + la] / ca;
    out[(size_t)Bd * NSd * Cd + t] = sums[plane + lb] / cb;
    if (t < Bd * NSd)
        out[2 * (size_t)Bd * NSd * Cd + t] = ew[t];
}

extern "C" void kernel_launch(void* const* d_in, const int* in_sizes, int n_in,
                              void* d_out, int out_size, void* d_ws, size_t ws_size,
                              hipStream_t stream) {
    const float* x     = (const float*)d_in[0];   // [B,C,H,W] f32
    const int*   lab   = (const int*)d_in[1];     // [B,1,H,W] i32
    const int*   edges = (const int*)d_in[2];     // [B,NS,2] i32
    const float* ew    = (const float*)d_in[3];   // [B,NS] f32
    float*       out   = (float*)d_out;

    const int n_gather = Bd * NSd * Cd;   // 524288

    if (ws_size >= (size_t)WS_ELEMS * sizeof(int)) {
        int*      wsi    = (int*)d_ws;
        int*      cnt    = wsi + OFF_CNT;
        int*      start  = wsi + OFF_START;
        int*      cursor = wsi + OFF_CURSOR;
        int*      perm   = wsi + OFF_PERM;
        float*    means  = (float*)(wsi + OFF_MEANS);
        unsigned* xt     = (unsigned*)(wsi + OFF_XT);

        hipMemsetAsync(cnt, 0, (size_t)Bd * NLd * sizeof(int), stream);

        hist_kernel<<<dim3(4, Bd), 256, 0, stream>>>(lab, cnt);
        scan_kernel<<<Bd, 1024, 0, stream>>>(cnt, start, cursor);
        scatter_kernel<<<(Bd * HWp) / 256, 256, 0, stream>>>(lab, cursor, perm);
        for (int b = 0; b < Bd; ++b) {
            transpose_kernel<<<HWp / 64, 256, 0, stream>>>(x, xt, b);
            sum_kernel<<<NLd / 4, 256, 0, stream>>>(xt, cnt, start, perm, means, b);
        }
        gather_kernel<<<n_gather / 256, 256, 0, stream>>>(means, edges, ew, out);
    } else {
        // ---- fallback: R1 atomic path ----
        float* sums   = (float*)d_ws;
        float* counts = sums + (size_t)Bd * Cd * NLd;

        hipMemsetAsync(d_ws, 0, (size_t)WS_FB_ELEMS * sizeof(float), stream);

        fb_sums_kernel<<<dim3(4, Cd, Bd), 256, 0, stream>>>(x, lab, sums);
        fb_counts_kernel<<<dim3(4, Bd), 256, 0, stream>>>(lab, counts);
        fb_gather_kernel<<<n_gather / 256, 256, 0, stream>>>(sums, counts, edges, ew, out);
    }
}

// Round 6
// 169.827 us; speedup vs baseline: 3.1151x; 2.0783x over previous
//
#include <hip/hip_runtime.h>

// Problem constants (fixed by the reference setup)
#define Bd 4
#define Cd 64
#define HWp 262144           // 512*512 = 2^18 pixels per image
#define NSd 2048
#define NLd 1000

// Sort geometry: 64 blocks total, 16 per image, 16384 pixels per block.
#define NBLK   64
#define JB     16            // blocks per image
#define PXB    16384         // pixels per block
#define PXB4   (PXB / 4)     // int4 per block

// ===========================================================================
// FAST PATH: deterministic counting sort (no global atomics)
//            + pixel-major bf16 transpose + coalesced label sums
// ws layout (int-element offsets). blockCnt/blockBase alias the xt region:
// they are consumed by scatter_kernel before transpose_kernel writes xt.
//   cnt       [B*NL]      int
//   start     [B*NL]      int
//   perm      [B*HW]      int
//   means     [B*NL*C]    float
//   xt        [HW*C/2]    u32   (one image, reused; also hosts blockCnt/Base)
// ===========================================================================
#define OFF_CNT    0
#define OFF_START  (Bd * NLd)
#define OFF_PERM   (2 * Bd * NLd)
#define OFF_MEANS  (2 * Bd * NLd + Bd * HWp)
#define OFF_XT     (OFF_MEANS + Bd * NLd * Cd)
#define OFF_BCNT   OFF_XT                       // [NBLK*NL] int (aliased)
#define OFF_BBASE  (OFF_XT + NBLK * NLd)        // [NBLK*NL] int (aliased)
// keep the R5-proven workspace requirement (new layout is slightly smaller)
#define WS_ELEMS   (3 * Bd * NLd + Bd * HWp + Bd * NLd * Cd + HWp * Cd / 2)

__device__ __forceinline__ unsigned short f2bf(float f) {
    unsigned u = __float_as_uint(f);
    u += 0x7FFFu + ((u >> 16) & 1u);          // round-to-nearest-even
    return (unsigned short)(u >> 16);
}
__device__ __forceinline__ float bflo(unsigned u) { return __uint_as_float(u << 16); }
__device__ __forceinline__ float bfhi(unsigned u) { return __uint_as_float(u & 0xFFFF0000u); }
__device__ __forceinline__ int clampl(int l) {
    return (l < 0) ? 0 : (l >= NLd ? NLd - 1 : l);
}

// ---------------------------------------------------------------------------
// 1) per-block label histogram. grid = NBLK, block = 256.
// ---------------------------------------------------------------------------
__global__ __launch_bounds__(256)
void blockcnt_kernel(const int* __restrict__ lab, int* __restrict__ blockCnt) {
    __shared__ unsigned h[NLd];
    const int tid = threadIdx.x;
    const int g   = blockIdx.x;              // 0..NBLK-1

    for (int l = tid; l < NLd; l += 256) h[l] = 0u;
    __syncthreads();

    const int4* __restrict__ lp = (const int4*)lab + (size_t)g * PXB4;
    for (int v = tid; v < PXB4; v += 256) {
        int4 lv = lp[v];
        atomicAdd(&h[clampl(lv.x)], 1u);
        atomicAdd(&h[clampl(lv.y)], 1u);
        atomicAdd(&h[clampl(lv.z)], 1u);
        atomicAdd(&h[clampl(lv.w)], 1u);
    }
    __syncthreads();

    int* __restrict__ dst = blockCnt + (size_t)g * NLd;
    for (int l = tid; l < NLd; l += 256) dst[l] = (int)h[l];
}

// ---------------------------------------------------------------------------
// 2) per-image: label totals over JB blocks -> exclusive scan -> start/cnt,
//    plus per-block bases. grid = B, block = 1024. Pure arithmetic, no atomics.
// ---------------------------------------------------------------------------
__global__ __launch_bounds__(1024)
void scan_kernel(const int* __restrict__ blockCnt, int* __restrict__ cnt,
                 int* __restrict__ start, int* __restrict__ blockBase) {
    __shared__ int buf[1024];
    const int tid = threadIdx.x;
    const int b   = blockIdx.x;

    int total = 0;
    if (tid < NLd) {
        #pragma unroll
        for (int j = 0; j < JB; ++j)
            total += blockCnt[(size_t)(b * JB + j) * NLd + tid];
    }
    buf[tid] = (tid < NLd) ? total : 0;
    __syncthreads();
    for (int off = 1; off < 1024; off <<= 1) {
        int t = (tid >= off) ? buf[tid - off] : 0;
        __syncthreads();
        buf[tid] += t;
        __syncthreads();
    }
    if (tid < NLd) {
        int st = buf[tid] - total;             // exclusive prefix
        start[b * NLd + tid] = st;
        cnt[b * NLd + tid]   = total;
        int run = st;
        #pragma unroll
        for (int j = 0; j < JB; ++j) {
            const size_t idx = (size_t)(b * JB + j) * NLd + tid;
            blockBase[idx] = run;
            run += blockCnt[idx];
        }
    }
}

// ---------------------------------------------------------------------------
// 3) scatter: local rank via LDS atomic, deterministic global base.
//    grid = NBLK, block = 256. Zero global atomics.
// ---------------------------------------------------------------------------
__global__ __launch_bounds__(256)
void scatter_kernel(const int* __restrict__ lab, const int* __restrict__ blockBase,
                    int* __restrict__ perm) {
    __shared__ unsigned h[NLd];
    __shared__ int base[NLd];
    const int tid = threadIdx.x;
    const int g   = blockIdx.x;              // 0..NBLK-1
    const int b   = g / JB;
    const int p0  = (g % JB) * PXB;          // local pixel offset in image

    for (int l = tid; l < NLd; l += 256) {
        h[l] = 0u;
        base[l] = blockBase[(size_t)g * NLd + l];
    }
    __syncthreads();

    const int4* __restrict__ lp = (const int4*)(lab + ((size_t)b << 18) + p0);
    int* __restrict__ pb = perm + ((size_t)b << 18);

    for (int v = tid; v < PXB4; v += 256) {
        int4 lv = lp[v];
        const int p = p0 + 4 * v;
        int l0 = clampl(lv.x), l1 = clampl(lv.y), l2 = clampl(lv.z), l3 = clampl(lv.w);
        int r0 = (int)atomicAdd(&h[l0], 1u);
        int r1 = (int)atomicAdd(&h[l1], 1u);
        int r2 = (int)atomicAdd(&h[l2], 1u);
        int r3 = (int)atomicAdd(&h[l3], 1u);
        int i0 = base[l0] + r0; i0 = (i0 < 0) ? 0 : (i0 >= HWp ? HWp - 1 : i0);
        int i1 = base[l1] + r1; i1 = (i1 < 0) ? 0 : (i1 >= HWp ? HWp - 1 : i1);
        int i2 = base[l2] + r2; i2 = (i2 < 0) ? 0 : (i2 >= HWp ? HWp - 1 : i2);
        int i3 = base[l3] + r3; i3 = (i3 < 0) ? 0 : (i3 >= HWp ? HWp - 1 : i3);
        pb[i0] = p + 0;
        pb[i1] = p + 1;
        pb[i2] = p + 2;
        pb[i3] = p + 3;
    }
}

// ---------------------------------------------------------------------------
// Transpose one image: x[b][C][HW] f32 -> xt[HW][C] bf16 (packed u32 pairs).
// ---------------------------------------------------------------------------
__global__ __launch_bounds__(256)
void transpose_kernel(const float* __restrict__ x, unsigned* __restrict__ xt, int b) {
    __shared__ float lds[64 * 65];
    const int tid = threadIdx.x;
    const int p0  = blockIdx.x * 64;
    const float* __restrict__ xb = x + ((size_t)b * Cd << 18);

    #pragma unroll
    for (int it = 0; it < 4; ++it) {
        const int c = it * 16 + (tid >> 4);
        const int j = tid & 15;
        float4 v = *(const float4*)(xb + ((size_t)c << 18) + p0 + 4 * j);
        lds[(4 * j + 0) * 65 + c] = v.x;
        lds[(4 * j + 1) * 65 + c] = v.y;
        lds[(4 * j + 2) * 65 + c] = v.z;
        lds[(4 * j + 3) * 65 + c] = v.w;
    }
    __syncthreads();

    #pragma unroll
    for (int it = 0; it < 8; ++it) {
        const int p  = it * 8 + (tid >> 5);
        const int cp = tid & 31;
        float lo = lds[p * 65 + 2 * cp];
        float hi = lds[p * 65 + 2 * cp + 1];
        unsigned packed = ((unsigned)f2bf(hi) << 16) | (unsigned)f2bf(lo);
        xt[(size_t)(p0 + p) * 32 + cp] = packed;
    }
}

// ---------------------------------------------------------------------------
// Per-image label sums over xt. grid = 250, block = 256 (wave per label).
// ---------------------------------------------------------------------------
__global__ __launch_bounds__(256)
void sum_kernel(const unsigned* __restrict__ xt, const int* __restrict__ cnt,
                const int* __restrict__ start, const int* __restrict__ perm,
                float* __restrict__ means, int b) {
    __shared__ int sperm[3072];
    const int tid  = threadIdx.x;
    const int l0   = blockIdx.x * 4;
    const int lane = tid & 63;
    const int w    = tid >> 6;
    const int l    = l0 + w;

    int sB = start[b * NLd + l0];
    const int lastI = b * NLd + l0 + 3;
    int sE = start[lastI] + cnt[lastI];
    if (sB < 0) sB = 0; if (sB > HWp) sB = HWp;
    int tot = sE - sB;
    if (tot < 0) tot = 0;
    if (tot > HWp - sB) tot = HWp - sB;
    const int stg = tot > 3072 ? 3072 : tot;

    const int* __restrict__ gp = perm + ((size_t)b << 18);
    for (int t = tid; t < stg; t += 256) sperm[t] = gp[sB + t];
    __syncthreads();

    int n = cnt[b * NLd + l];
    int s = start[b * NLd + l];
    if (s < sB) s = sB; if (s > HWp) s = HWp;
    if (n < 0) n = 0;
    if (n > HWp - s) n = HWp - s;
    const int off = s - sB;

    const int half = lane >> 5;
    const int cp   = lane & 31;

    float s0a = 0, s1a = 0, s0b = 0, s1b = 0, s0c = 0, s1c = 0, s0d = 0, s1d = 0;
    float s0e = 0, s1e = 0, s0f = 0, s1f = 0, s0g = 0, s1g = 0, s0h = 0, s1h = 0;

    int i = 0;
    for (; i + 16 <= n; i += 16) {
        int pA, pB, pC, pD, pE, pF, pG, pH;
        if (off + i + 16 <= stg) {
            const int base = off + i + half;
            pA = sperm[base +  0]; pB = sperm[base +  2];
            pC = sperm[base +  4]; pD = sperm[base +  6];
            pE = sperm[base +  8]; pF = sperm[base + 10];
            pG = sperm[base + 12]; pH = sperm[base + 14];
        } else {
            const int base = s + i + half;
            pA = gp[base +  0]; pB = gp[base +  2];
            pC = gp[base +  4]; pD = gp[base +  6];
            pE = gp[base +  8]; pF = gp[base + 10];
            pG = gp[base + 12]; pH = gp[base + 14];
        }
        unsigned uA = xt[(size_t)pA * 32 + cp];
        unsigned uB = xt[(size_t)pB * 32 + cp];
        unsigned uC = xt[(size_t)pC * 32 + cp];
        unsigned uD = xt[(size_t)pD * 32 + cp];
        unsigned uE = xt[(size_t)pE * 32 + cp];
        unsigned uF = xt[(size_t)pF * 32 + cp];
        unsigned uG = xt[(size_t)pG * 32 + cp];
        unsigned uH = xt[(size_t)pH * 32 + cp];
        s0a += bflo(uA); s1a += bfhi(uA);
        s0b += bflo(uB); s1b += bfhi(uB);
        s0c += bflo(uC); s1c += bfhi(uC);
        s0d += bflo(uD); s1d += bfhi(uD);
        s0e += bflo(uE); s1e += bfhi(uE);
        s0f += bflo(uF); s1f += bfhi(uF);
        s0g += bflo(uG); s1g += bfhi(uG);
        s0h += bflo(uH); s1h += bfhi(uH);
    }
    for (; i + 2 <= n; i += 2) {
        const int idx = off + i + half;
        const int p = (idx < stg) ? sperm[idx] : gp[s + i + half];
        unsigned u = xt[(size_t)p * 32 + cp];
        s0a += bflo(u); s1a += bfhi(u);
    }
    if (i < n && half == 0) {
        const int idx = off + i;
        const int p = (idx < stg) ? sperm[idx] : gp[s + i];
        unsigned u = xt[(size_t)p * 32 + cp];
        s0a += bflo(u); s1a += bfhi(u);
    }

    float a0 = ((s0a + s0b) + (s0c + s0d)) + ((s0e + s0f) + (s0g + s0h));
    float a1 = ((s1a + s1b) + (s1c + s1d)) + ((s1e + s1f) + (s1g + s1h));
    a0 += __shfl_xor(a0, 32, 64);
    a1 += __shfl_xor(a1, 32, 64);

    if (half == 0) {
        const float inv = 1.0f / (float)(n > 0 ? n : 1);
        float2 o; o.x = a0 * inv; o.y = a1 * inv;
        *(float2*)(means + (((size_t)(b * NLd + l)) << 6) + 2 * cp) = o;
    }
}

__global__ __launch_bounds__(256)
void gather_kernel(const float* __restrict__ means,
                   const int* __restrict__ edges,
                   const float* __restrict__ ew,
                   float* __restrict__ out) {
    const int t  = blockIdx.x * 256 + threadIdx.x;   // 0 .. B*NS*C-1
    const int bs = t >> 6;                           // b*NS + s
    const int c  = t & 63;
    const int b  = bs >> 11;                         // NS = 2048

    const int la = clampl(edges[bs * 2 + 0]);
    const int lb = clampl(edges[bs * 2 + 1]);

    out[t] = means[((size_t)(b * NLd + la) << 6) + c];
    out[(size_t)Bd * NSd * Cd + t] = means[((size_t)(b * NLd + lb) << 6) + c];
    if (t < Bd * NSd)
        out[2 * (size_t)Bd * NSd * Cd + t] = ew[t];
}

// ===========================================================================
// FALLBACK PATH (R1 design, known-good 371 us; needs ~1 MB ws)
// ===========================================================================
#define WS_FB_ELEMS (Bd * Cd * NLd + Bd * NLd)

__global__ __launch_bounds__(256)
void fb_sums_kernel(const float* __restrict__ x, const int* __restrict__ lab,
                    float* __restrict__ sums) {
    __shared__ float lsum[NLd];
    const int tid   = threadIdx.x;
    const int chunk = blockIdx.x;
    const int c     = blockIdx.y;
    const int b     = blockIdx.z;

    for (int l = tid; l < NLd; l += 256) lsum[l] = 0.0f;
    __syncthreads();

    const float4* __restrict__ xp =
        (const float4*)x + (size_t)(b * Cd + c) * (HWp / 4);
    const int4* __restrict__ lp = (const int4*)lab + (size_t)b * (HWp / 4);

    const int nvec = HWp / 16;
    const int v0 = chunk * nvec, v1 = v0 + nvec;
    for (int v = v0 + tid; v < v1; v += 256) {
        float4 xv = xp[v];
        int4   lv = lp[v];
        atomicAdd(&lsum[clampl(lv.x)], xv.x);
        atomicAdd(&lsum[clampl(lv.y)], xv.y);
        atomicAdd(&lsum[clampl(lv.z)], xv.z);
        atomicAdd(&lsum[clampl(lv.w)], xv.w);
    }
    __syncthreads();

    float* __restrict__ dst = sums + (size_t)(b * Cd + c) * NLd;
    for (int l = tid; l < NLd; l += 256)
        atomicAdd(&dst[l], lsum[l]);
}

__global__ __launch_bounds__(256)
void fb_counts_kernel(const int* __restrict__ lab, float* __restrict__ counts) {
    __shared__ unsigned lcnt[NLd];
    const int tid   = threadIdx.x;
    const int chunk = blockIdx.x;
    const int b     = blockIdx.y;

    for (int l = tid; l < NLd; l += 256) lcnt[l] = 0u;
    __syncthreads();

    const int4* __restrict__ lp = (const int4*)lab + (size_t)b * (HWp / 4);
    const int nvec = HWp / 16;
    const int v0 = chunk * nvec, v1 = v0 + nvec;
    for (int v = v0 + tid; v < v1; v += 256) {
        int4 lv = lp[v];
        atomicAdd(&lcnt[clampl(lv.x)], 1u);
        atomicAdd(&lcnt[clampl(lv.y)], 1u);
        atomicAdd(&lcnt[clampl(lv.z)], 1u);
        atomicAdd(&lcnt[clampl(lv.w)], 1u);
    }
    __syncthreads();

    float* __restrict__ dst = counts + (size_t)b * NLd;
    for (int l = tid; l < NLd; l += 256)
        atomicAdd(&dst[l], (float)lcnt[l]);
}

__global__ __launch_bounds__(256)
void fb_gather_kernel(const float* __restrict__ sums,
                      const float* __restrict__ counts,
                      const int* __restrict__ edges,
                      const float* __restrict__ ew,
                      float* __restrict__ out) {
    const int t  = blockIdx.x * 256 + threadIdx.x;
    const int bs = t >> 6;
    const int c  = t & 63;
    const int b  = bs >> 11;

    const int la = clampl(edges[bs * 2 + 0]);
    const int lb = clampl(edges[bs * 2 + 1]);

    const float ca = fmaxf(counts[b * NLd + la], 1.0f);
    const float cb = fmaxf(counts[b * NLd + lb], 1.0f);

    const size_t plane = (size_t)(b * Cd + c) * NLd;
    out[t] = sums[plane + la] / ca;
    out[(size_t)Bd * NSd * Cd + t] = sums[plane + lb] / cb;
    if (t < Bd * NSd)
        out[2 * (size_t)Bd * NSd * Cd + t] = ew[t];
}

extern "C" void kernel_launch(void* const* d_in, const int* in_sizes, int n_in,
                              void* d_out, int out_size, void* d_ws, size_t ws_size,
                              hipStream_t stream) {
    const float* x     = (const float*)d_in[0];   // [B,C,H,W] f32
    const int*   lab   = (const int*)d_in[1];     // [B,1,H,W] i32
    const int*   edges = (const int*)d_in[2];     // [B,NS,2] i32
    const float* ew    = (const float*)d_in[3];   // [B,NS] f32
    float*       out   = (float*)d_out;

    const int n_gather = Bd * NSd * Cd;   // 524288

    if (ws_size >= (size_t)WS_ELEMS * sizeof(int)) {
        int*      wsi       = (int*)d_ws;
        int*      cnt       = wsi + OFF_CNT;
        int*      start     = wsi + OFF_START;
        int*      perm      = wsi + OFF_PERM;
        float*    means     = (float*)(wsi + OFF_MEANS);
        unsigned* xt        = (unsigned*)(wsi + OFF_XT);
        int*      blockCnt  = wsi + OFF_BCNT;    // aliases xt (dead before xt)
        int*      blockBase = wsi + OFF_BBASE;   // aliases xt (dead before xt)

        blockcnt_kernel<<<NBLK, 256, 0, stream>>>(lab, blockCnt);
        scan_kernel<<<Bd, 1024, 0, stream>>>(blockCnt, cnt, start, blockBase);
        scatter_kernel<<<NBLK, 256, 0, stream>>>(lab, blockBase, perm);
        for (int b = 0; b < Bd; ++b) {
            transpose_kernel<<<HWp / 64, 256, 0, stream>>>(x, xt, b);
            sum_kernel<<<NLd / 4, 256, 0, stream>>>(xt, cnt, start, perm, means, b);
        }
        gather_kernel<<<n_gather / 256, 256, 0, stream>>>(means, edges, ew, out);
    } else {
        // ---- fallback: R1 atomic path ----
        float* sums   = (float*)d_ws;
        float* counts = sums + (size_t)Bd * Cd * NLd;

        hipMemsetAsync(d_ws, 0, (size_t)WS_FB_ELEMS * sizeof(float), stream);

        fb_sums_kernel<<<dim3(4, Cd, Bd), 256, 0, stream>>>(x, lab, sums);
        fb_counts_kernel<<<dim3(4, Bd), 256, 0, stream>>>(lab, counts);
        fb_gather_kernel<<<n_gather / 256, 256, 0, stream>>>(sums, counts, edges, ew, out);
    }
}

// Round 7
// 133.655 us; speedup vs baseline: 3.9581x; 1.2706x over previous
//
#include <hip/hip_runtime.h>

// Problem constants (fixed by the reference setup)
#define Bd 4
#define Cd 64
#define HWp 262144           // 512*512 = 2^18 pixels per image
#define NSd 2048
#define NLd 1000

// Sort geometry: 64 blocks total, 16 per image, 16384 pixels per block.
#define NBLK   64
#define JB     16            // blocks per image
#define PXB    16384         // pixels per block
#define PXB4   (PXB / 4)     // int4 per block

// ===========================================================================
// FAST PATH:
//   sort -> rank[pixel] (coalesced), transpose scatters pixel channel-rows
//   to sorted positions (full 128B lines), sum = sequential stream, gather.
// ws layout (int-element offsets):
//   cnt       [B*NL]        int
//   start     [B*NL]        int
//   blockCnt  [NBLK*NL]     int
//   blockBase [NBLK*NL]     int
//   rank      [B*HW]        int    sorted position of each pixel
//   means     [B*NL*C]      float
//   xt        [B*HW*C/2]    u32    bf16 pairs, rows ordered by rank
// ===========================================================================
#define OFF_CNT    0
#define OFF_START  (Bd * NLd)
#define OFF_BCNT   (2 * Bd * NLd)
#define OFF_BBASE  (2 * Bd * NLd + NBLK * NLd)
#define OFF_RANK   (2 * Bd * NLd + 2 * NBLK * NLd)
#define OFF_MEANS  (OFF_RANK + Bd * HWp)
#define OFF_XT     (OFF_MEANS + Bd * NLd * Cd)
#define WS_ELEMS   (OFF_XT + Bd * HWp * (Cd / 2))

__device__ __forceinline__ unsigned short f2bf(float f) {
    unsigned u = __float_as_uint(f);
    u += 0x7FFFu + ((u >> 16) & 1u);          // round-to-nearest-even
    return (unsigned short)(u >> 16);
}
__device__ __forceinline__ float bflo(unsigned u) { return __uint_as_float(u << 16); }
__device__ __forceinline__ float bfhi(unsigned u) { return __uint_as_float(u & 0xFFFF0000u); }
__device__ __forceinline__ int clampl(int l) {
    return (l < 0) ? 0 : (l >= NLd ? NLd - 1 : l);
}

// ---------------------------------------------------------------------------
// 1) per-block label histogram. grid = NBLK, block = 256.
// ---------------------------------------------------------------------------
__global__ __launch_bounds__(256)
void blockcnt_kernel(const int* __restrict__ lab, int* __restrict__ blockCnt) {
    __shared__ unsigned h[NLd];
    const int tid = threadIdx.x;
    const int g   = blockIdx.x;

    for (int l = tid; l < NLd; l += 256) h[l] = 0u;
    __syncthreads();

    const int4* __restrict__ lp = (const int4*)lab + (size_t)g * PXB4;
    for (int v = tid; v < PXB4; v += 256) {
        int4 lv = lp[v];
        atomicAdd(&h[clampl(lv.x)], 1u);
        atomicAdd(&h[clampl(lv.y)], 1u);
        atomicAdd(&h[clampl(lv.z)], 1u);
        atomicAdd(&h[clampl(lv.w)], 1u);
    }
    __syncthreads();

    int* __restrict__ dst = blockCnt + (size_t)g * NLd;
    for (int l = tid; l < NLd; l += 256) dst[l] = (int)h[l];
}

// ---------------------------------------------------------------------------
// 2) per-image totals + exclusive scan + per-block bases. grid = B.
// ---------------------------------------------------------------------------
__global__ __launch_bounds__(1024)
void scan_kernel(const int* __restrict__ blockCnt, int* __restrict__ cnt,
                 int* __restrict__ start, int* __restrict__ blockBase) {
    __shared__ int buf[1024];
    const int tid = threadIdx.x;
    const int b   = blockIdx.x;

    int total = 0;
    if (tid < NLd) {
        #pragma unroll
        for (int j = 0; j < JB; ++j)
            total += blockCnt[(size_t)(b * JB + j) * NLd + tid];
    }
    buf[tid] = (tid < NLd) ? total : 0;
    __syncthreads();
    for (int off = 1; off < 1024; off <<= 1) {
        int t = (tid >= off) ? buf[tid - off] : 0;
        __syncthreads();
        buf[tid] += t;
        __syncthreads();
    }
    if (tid < NLd) {
        int st = buf[tid] - total;
        start[b * NLd + tid] = st;
        cnt[b * NLd + tid]   = total;
        int run = st;
        #pragma unroll
        for (int j = 0; j < JB; ++j) {
            const size_t idx = (size_t)(b * JB + j) * NLd + tid;
            blockBase[idx] = run;
            run += blockCnt[idx];
        }
    }
}

// ---------------------------------------------------------------------------
// 3) rank: sorted position per pixel. Coalesced int4 writes, no global atomics.
// ---------------------------------------------------------------------------
__global__ __launch_bounds__(256)
void rank_kernel(const int* __restrict__ lab, const int* __restrict__ blockBase,
                 int* __restrict__ rank) {
    __shared__ unsigned h[NLd];
    __shared__ int base[NLd];
    const int tid = threadIdx.x;
    const int g   = blockIdx.x;
    const int b   = g / JB;
    const int p0  = (g % JB) * PXB;

    for (int l = tid; l < NLd; l += 256) {
        h[l] = 0u;
        base[l] = blockBase[(size_t)g * NLd + l];
    }
    __syncthreads();

    const int4* __restrict__ lp = (const int4*)(lab + ((size_t)b << 18) + p0);
    int4* __restrict__ rp = (int4*)(rank + ((size_t)b << 18) + p0);

    for (int v = tid; v < PXB4; v += 256) {
        int4 lv = lp[v];
        int l0 = clampl(lv.x), l1 = clampl(lv.y), l2 = clampl(lv.z), l3 = clampl(lv.w);
        int4 rv;
        rv.x = base[l0] + (int)atomicAdd(&h[l0], 1u);
        rv.y = base[l1] + (int)atomicAdd(&h[l1], 1u);
        rv.z = base[l2] + (int)atomicAdd(&h[l2], 1u);
        rv.w = base[l3] + (int)atomicAdd(&h[l3], 1u);
        rv.x = (rv.x < 0) ? 0 : (rv.x >= HWp ? HWp - 1 : rv.x);
        rv.y = (rv.y < 0) ? 0 : (rv.y >= HWp ? HWp - 1 : rv.y);
        rv.z = (rv.z < 0) ? 0 : (rv.z >= HWp ? HWp - 1 : rv.z);
        rv.w = (rv.w < 0) ? 0 : (rv.w >= HWp ? HWp - 1 : rv.w);
        rp[v] = rv;
    }
}

// ---------------------------------------------------------------------------
// 4) transpose + scatter: x[b][C][HW] f32 -> xt[b][rank[p]][C] bf16 pairs.
//    grid = (HW/64, B), block = 256. Each pixel's 32 u32 = one full 128B
//    line written by 32 lanes of one wave (2 pixels per wave-instruction).
// ---------------------------------------------------------------------------
__global__ __launch_bounds__(256)
void transpose_kernel(const float* __restrict__ x, const int* __restrict__ rank,
                      unsigned* __restrict__ xt) {
    __shared__ float lds[64 * 65];
    __shared__ int rnk[64];
    const int tid = threadIdx.x;
    const int p0  = blockIdx.x * 64;
    const int b   = blockIdx.y;
    const float* __restrict__ xb = x + ((size_t)b * Cd << 18);

    if (tid < 64) rnk[tid] = rank[((size_t)b << 18) + p0 + tid];

    #pragma unroll
    for (int it = 0; it < 4; ++it) {
        const int c = it * 16 + (tid >> 4);
        const int j = tid & 15;
        float4 v = *(const float4*)(xb + ((size_t)c << 18) + p0 + 4 * j);
        lds[(4 * j + 0) * 65 + c] = v.x;
        lds[(4 * j + 1) * 65 + c] = v.y;
        lds[(4 * j + 2) * 65 + c] = v.z;
        lds[(4 * j + 3) * 65 + c] = v.w;
    }
    __syncthreads();

    unsigned* __restrict__ xb_t = xt + (((size_t)b << 18) << 5);   // b*HW*32
    #pragma unroll
    for (int it = 0; it < 8; ++it) {
        const int p  = it * 8 + (tid >> 5);
        const int cp = tid & 31;
        float lo = lds[p * 65 + 2 * cp];
        float hi = lds[p * 65 + 2 * cp + 1];
        unsigned packed = ((unsigned)f2bf(hi) << 16) | (unsigned)f2bf(lo);
        xb_t[((size_t)rnk[p] << 5) + cp] = packed;
    }
}

// ---------------------------------------------------------------------------
// 5) label sums: pure sequential stream over xt rows [start, start+n).
//    grid = (250, B), block = 256; wave w -> label bid*4+w.
//    Lane = (pixslot 0..7, q 0..7): uint4 per lane -> 8 pixels x 128B per
//    wave-load, fully coalesced. 3-step shfl reduce over pixslot.
// ---------------------------------------------------------------------------
__global__ __launch_bounds__(256)
void sum_kernel(const unsigned* __restrict__ xt, const int* __restrict__ cnt,
                const int* __restrict__ start, float* __restrict__ means) {
    const int tid  = threadIdx.x;
    const int b    = blockIdx.y;
    const int l    = blockIdx.x * 4 + (tid >> 6);
    const int lane = tid & 63;
    const int ps   = lane >> 3;     // pixel slot 0..7
    const int q    = lane & 7;      // uint4 slot within row (8 channels)

    int n = cnt[b * NLd + l];
    int s = start[b * NLd + l];
    if (s < 0) s = 0; if (s > HWp) s = HWp;
    if (n < 0) n = 0;
    if (n > HWp - s) n = HWp - s;

    const uint4* __restrict__ xb =
        (const uint4*)(xt + (((size_t)b << 18) << 5)) + ((size_t)s << 3) + q;

    float a0 = 0, a1 = 0, a2 = 0, a3 = 0, a4 = 0, a5 = 0, a6 = 0, a7 = 0;
    for (int i = 0; i < n; i += 8) {
        const int pix = i + ps;
        if (pix < n) {
            uint4 u = xb[(size_t)pix << 3];
            a0 += bflo(u.x); a1 += bfhi(u.x);
            a2 += bflo(u.y); a3 += bfhi(u.y);
            a4 += bflo(u.z); a5 += bfhi(u.z);
            a6 += bflo(u.w); a7 += bfhi(u.w);
        }
    }

    #pragma unroll
    for (int off = 8; off < 64; off <<= 1) {
        a0 += __shfl_xor(a0, off, 64);
        a1 += __shfl_xor(a1, off, 64);
        a2 += __shfl_xor(a2, off, 64);
        a3 += __shfl_xor(a3, off, 64);
        a4 += __shfl_xor(a4, off, 64);
        a5 += __shfl_xor(a5, off, 64);
        a6 += __shfl_xor(a6, off, 64);
        a7 += __shfl_xor(a7, off, 64);
    }

    if (ps == 0) {
        const float inv = 1.0f / (float)(n > 0 ? n : 1);
        float* dst = means + (((size_t)(b * NLd + l)) << 6) + q * 8;
        float4 o0; o0.x = a0 * inv; o0.y = a1 * inv; o0.z = a2 * inv; o0.w = a3 * inv;
        float4 o1; o1.x = a4 * inv; o1.y = a5 * inv; o1.z = a6 * inv; o1.w = a7 * inv;
        *(float4*)dst = o0;
        *(float4*)(dst + 4) = o1;
    }
}

__global__ __launch_bounds__(256)
void gather_kernel(const float* __restrict__ means,
                   const int* __restrict__ edges,
                   const float* __restrict__ ew,
                   float* __restrict__ out) {
    const int t  = blockIdx.x * 256 + threadIdx.x;   // 0 .. B*NS*C-1
    const int bs = t >> 6;                           // b*NS + s
    const int c  = t & 63;
    const int b  = bs >> 11;                         // NS = 2048

    const int la = clampl(edges[bs * 2 + 0]);
    const int lb = clampl(edges[bs * 2 + 1]);

    out[t] = means[((size_t)(b * NLd + la) << 6) + c];
    out[(size_t)Bd * NSd * Cd + t] = means[((size_t)(b * NLd + lb) << 6) + c];
    if (t < Bd * NSd)
        out[2 * (size_t)Bd * NSd * Cd + t] = ew[t];
}

// ===========================================================================
// FALLBACK PATH (R1 design, known-good 371 us; needs ~1 MB ws)
// ===========================================================================
#define WS_FB_ELEMS (Bd * Cd * NLd + Bd * NLd)

__global__ __launch_bounds__(256)
void fb_sums_kernel(const float* __restrict__ x, const int* __restrict__ lab,
                    float* __restrict__ sums) {
    __shared__ float lsum[NLd];
    const int tid   = threadIdx.x;
    const int chunk = blockIdx.x;
    const int c     = blockIdx.y;
    const int b     = blockIdx.z;

    for (int l = tid; l < NLd; l += 256) lsum[l] = 0.0f;
    __syncthreads();

    const float4* __restrict__ xp =
        (const float4*)x + (size_t)(b * Cd + c) * (HWp / 4);
    const int4* __restrict__ lp = (const int4*)lab + (size_t)b * (HWp / 4);

    const int nvec = HWp / 16;
    const int v0 = chunk * nvec, v1 = v0 + nvec;
    for (int v = v0 + tid; v < v1; v += 256) {
        float4 xv = xp[v];
        int4   lv = lp[v];
        atomicAdd(&lsum[clampl(lv.x)], xv.x);
        atomicAdd(&lsum[clampl(lv.y)], xv.y);
        atomicAdd(&lsum[clampl(lv.z)], xv.z);
        atomicAdd(&lsum[clampl(lv.w)], xv.w);
    }
    __syncthreads();

    float* __restrict__ dst = sums + (size_t)(b * Cd + c) * NLd;
    for (int l = tid; l < NLd; l += 256)
        atomicAdd(&dst[l], lsum[l]);
}

__global__ __launch_bounds__(256)
void fb_counts_kernel(const int* __restrict__ lab, float* __restrict__ counts) {
    __shared__ unsigned lcnt[NLd];
    const int tid   = threadIdx.x;
    const int chunk = blockIdx.x;
    const int b     = blockIdx.y;

    for (int l = tid; l < NLd; l += 256) lcnt[l] = 0u;
    __syncthreads();

    const int4* __restrict__ lp = (const int4*)lab + (size_t)b * (HWp / 4);
    const int nvec = HWp / 16;
    const int v0 = chunk * nvec, v1 = v0 + nvec;
    for (int v = v0 + tid; v < v1; v += 256) {
        int4 lv = lp[v];
        atomicAdd(&lcnt[clampl(lv.x)], 1u);
        atomicAdd(&lcnt[clampl(lv.y)], 1u);
        atomicAdd(&lcnt[clampl(lv.z)], 1u);
        atomicAdd(&lcnt[clampl(lv.w)], 1u);
    }
    __syncthreads();

    float* __restrict__ dst = counts + (size_t)b * NLd;
    for (int l = tid; l < NLd; l += 256)
        atomicAdd(&dst[l], (float)lcnt[l]);
}

__global__ __launch_bounds__(256)
void fb_gather_kernel(const float* __restrict__ sums,
                      const float* __restrict__ counts,
                      const int* __restrict__ edges,
                      const float* __restrict__ ew,
                      float* __restrict__ out) {
    const int t  = blockIdx.x * 256 + threadIdx.x;
    const int bs = t >> 6;
    const int c  = t & 63;
    const int b  = bs >> 11;

    const int la = clampl(edges[bs * 2 + 0]);
    const int lb = clampl(edges[bs * 2 + 1]);

    const float ca = fmaxf(counts[b * NLd + la], 1.0f);
    const float cb = fmaxf(counts[b * NLd + lb], 1.0f);

    const size_t plane = (size_t)(b * Cd + c) * NLd;
    out[t] = sums[plane + la] / ca;
    out[(size_t)Bd * NSd * Cd + t] = sums[plane + lb] / cb;
    if (t < Bd * NSd)
        out[2 * (size_t)Bd * NSd * Cd + t] = ew[t];
}

extern "C" void kernel_launch(void* const* d_in, const int* in_sizes, int n_in,
                              void* d_out, int out_size, void* d_ws, size_t ws_size,
                              hipStream_t stream) {
    const float* x     = (const float*)d_in[0];   // [B,C,H,W] f32
    const int*   lab   = (const int*)d_in[1];     // [B,1,H,W] i32
    const int*   edges = (const int*)d_in[2];     // [B,NS,2] i32
    const float* ew    = (const float*)d_in[3];   // [B,NS] f32
    float*       out   = (float*)d_out;

    const int n_gather = Bd * NSd * Cd;   // 524288

    if (ws_size >= (size_t)WS_ELEMS * sizeof(int)) {
        int*      wsi       = (int*)d_ws;
        int*      cnt       = wsi + OFF_CNT;
        int*      start     = wsi + OFF_START;
        int*      blockCnt  = wsi + OFF_BCNT;
        int*      blockBase = wsi + OFF_BBASE;
        int*      rank      = wsi + OFF_RANK;
        float*    means     = (float*)(wsi + OFF_MEANS);
        unsigned* xt        = (unsigned*)(wsi + OFF_XT);

        blockcnt_kernel<<<NBLK, 256, 0, stream>>>(lab, blockCnt);
        scan_kernel<<<Bd, 1024, 0, stream>>>(blockCnt, cnt, start, blockBase);
        rank_kernel<<<NBLK, 256, 0, stream>>>(lab, blockBase, rank);
        transpose_kernel<<<dim3(HWp / 64, Bd), 256, 0, stream>>>(x, rank, xt);
        sum_kernel<<<dim3(NLd / 4, Bd), 256, 0, stream>>>(xt, cnt, start, means);
        gather_kernel<<<n_gather / 256, 256, 0, stream>>>(means, edges, ew, out);
    } else {
        // ---- fallback: R1 atomic path ----
        float* sums   = (float*)d_ws;
        float* counts = sums + (size_t)Bd * Cd * NLd;

        hipMemsetAsync(d_ws, 0, (size_t)WS_FB_ELEMS * sizeof(float), stream);

        fb_sums_kernel<<<dim3(4, Cd, Bd), 256, 0, stream>>>(x, lab, sums);
        fb_counts_kernel<<<dim3(4, Bd), 256, 0, stream>>>(lab, counts);
        fb_gather_kernel<<<n_gather / 256, 256, 0, stream>>>(sums, counts, edges, ew, out);
    }
}

// Round 8
// 117.074 us; speedup vs baseline: 4.5187x; 1.1416x over previous
//
#include <hip/hip_runtime.h>

// Problem constants (fixed by the reference setup)
#define Bd 4
#define Cd 64
#define HWp 262144           // 512*512 = 2^18 pixels per image
#define NSd 2048
#define NLd 1000

// Sort geometry: 256 blocks total, 64 per image, 4096 pixels per block.
#define NBLK   256
#define JB     64            // blocks per image
#define PXB    4096          // pixels per block
#define PXB4   (PXB / 4)     // int4 per block

typedef float  __attribute__((ext_vector_type(4))) floatx4;

// ===========================================================================
// FAST PATH:
//   sort -> rank[pixel] (coalesced), transpose scatters pixel channel-rows
//   to sorted positions (full 128B lines), sum = sequential stream, gather.
// ws layout (int-element offsets):
//   cnt       [B*NL]        int
//   start     [B*NL]        int
//   blockCnt  [NBLK*NL]     int
//   blockBase [NBLK*NL]     int
//   rank      [B*HW]        int    sorted position of each pixel
//   means     [B*NL*C]      float
//   xt        [B*HW*C/2]    u32    bf16 pairs, rows ordered by rank
// ===========================================================================
#define OFF_CNT    0
#define OFF_START  (Bd * NLd)
#define OFF_BCNT   (2 * Bd * NLd)
#define OFF_BBASE  (2 * Bd * NLd + NBLK * NLd)
#define OFF_RANK   (2 * Bd * NLd + 2 * NBLK * NLd)
#define OFF_MEANS  (OFF_RANK + Bd * HWp)
#define OFF_XT     (OFF_MEANS + Bd * NLd * Cd)
#define WS_ELEMS   (OFF_XT + Bd * HWp * (Cd / 2))

__device__ __forceinline__ unsigned short f2bf(float f) {
    unsigned u = __float_as_uint(f);
    u += 0x7FFFu + ((u >> 16) & 1u);          // round-to-nearest-even
    return (unsigned short)(u >> 16);
}
__device__ __forceinline__ float bflo(unsigned u) { return __uint_as_float(u << 16); }
__device__ __forceinline__ float bfhi(unsigned u) { return __uint_as_float(u & 0xFFFF0000u); }
__device__ __forceinline__ int clampl(int l) {
    return (l < 0) ? 0 : (l >= NLd ? NLd - 1 : l);
}

// ---------------------------------------------------------------------------
// 1) per-block label histogram. grid = NBLK, block = 256.
// ---------------------------------------------------------------------------
__global__ __launch_bounds__(256)
void blockcnt_kernel(const int* __restrict__ lab, int* __restrict__ blockCnt) {
    __shared__ unsigned h[NLd];
    const int tid = threadIdx.x;
    const int g   = blockIdx.x;

    for (int l = tid; l < NLd; l += 256) h[l] = 0u;
    __syncthreads();

    const int4* __restrict__ lp = (const int4*)lab + (size_t)g * PXB4;
    for (int v = tid; v < PXB4; v += 256) {
        int4 lv = lp[v];
        atomicAdd(&h[clampl(lv.x)], 1u);
        atomicAdd(&h[clampl(lv.y)], 1u);
        atomicAdd(&h[clampl(lv.z)], 1u);
        atomicAdd(&h[clampl(lv.w)], 1u);
    }
    __syncthreads();

    int* __restrict__ dst = blockCnt + (size_t)g * NLd;
    for (int l = tid; l < NLd; l += 256) dst[l] = (int)h[l];
}

// ---------------------------------------------------------------------------
// 2) per-image totals + exclusive scan + per-block bases. grid = B.
// ---------------------------------------------------------------------------
__global__ __launch_bounds__(1024)
void scan_kernel(const int* __restrict__ blockCnt, int* __restrict__ cnt,
                 int* __restrict__ start, int* __restrict__ blockBase) {
    __shared__ int buf[1024];
    const int tid = threadIdx.x;
    const int b   = blockIdx.x;

    int total = 0;
    if (tid < NLd) {
        for (int j = 0; j < JB; ++j)
            total += blockCnt[(size_t)(b * JB + j) * NLd + tid];
    }
    buf[tid] = (tid < NLd) ? total : 0;
    __syncthreads();
    for (int off = 1; off < 1024; off <<= 1) {
        int t = (tid >= off) ? buf[tid - off] : 0;
        __syncthreads();
        buf[tid] += t;
        __syncthreads();
    }
    if (tid < NLd) {
        int st = buf[tid] - total;
        start[b * NLd + tid] = st;
        cnt[b * NLd + tid]   = total;
        int run = st;
        for (int j = 0; j < JB; ++j) {
            const size_t idx = (size_t)(b * JB + j) * NLd + tid;
            blockBase[idx] = run;
            run += blockCnt[idx];
        }
    }
}

// ---------------------------------------------------------------------------
// 3) rank: sorted position per pixel. Coalesced int4 writes, no global atomics.
// ---------------------------------------------------------------------------
__global__ __launch_bounds__(256)
void rank_kernel(const int* __restrict__ lab, const int* __restrict__ blockBase,
                 int* __restrict__ rank) {
    __shared__ unsigned h[NLd];
    __shared__ int base[NLd];
    const int tid = threadIdx.x;
    const int g   = blockIdx.x;
    const int b   = g / JB;
    const int p0  = (g % JB) * PXB;

    for (int l = tid; l < NLd; l += 256) {
        h[l] = 0u;
        base[l] = blockBase[(size_t)g * NLd + l];
    }
    __syncthreads();

    const int4* __restrict__ lp = (const int4*)(lab + ((size_t)b << 18) + p0);
    int4* __restrict__ rp = (int4*)(rank + ((size_t)b << 18) + p0);

    for (int v = tid; v < PXB4; v += 256) {
        int4 lv = lp[v];
        int l0 = clampl(lv.x), l1 = clampl(lv.y), l2 = clampl(lv.z), l3 = clampl(lv.w);
        int4 rv;
        rv.x = base[l0] + (int)atomicAdd(&h[l0], 1u);
        rv.y = base[l1] + (int)atomicAdd(&h[l1], 1u);
        rv.z = base[l2] + (int)atomicAdd(&h[l2], 1u);
        rv.w = base[l3] + (int)atomicAdd(&h[l3], 1u);
        rv.x = (rv.x < 0) ? 0 : (rv.x >= HWp ? HWp - 1 : rv.x);
        rv.y = (rv.y < 0) ? 0 : (rv.y >= HWp ? HWp - 1 : rv.y);
        rv.z = (rv.z < 0) ? 0 : (rv.z >= HWp ? HWp - 1 : rv.z);
        rv.w = (rv.w < 0) ? 0 : (rv.w >= HWp ? HWp - 1 : rv.w);
        rp[v] = rv;
    }
}

// ---------------------------------------------------------------------------
// 4) transpose + scatter: x[b][C][HW] f32 -> xt[b][rank[p]][C] bf16 pairs.
//    grid = (HW/64, B), block = 256. x loads are NONTEMPORAL (read-once
//    256MB stream must not evict xt lines from L2/L3 before sum reads them).
//    Each pixel's 32 u32 = one full 128B line written by 32 lanes.
// ---------------------------------------------------------------------------
__global__ __launch_bounds__(256)
void transpose_kernel(const float* __restrict__ x, const int* __restrict__ rank,
                      unsigned* __restrict__ xt) {
    __shared__ float lds[64 * 65];
    __shared__ int rnk[64];
    const int tid = threadIdx.x;
    const int p0  = blockIdx.x * 64;
    const int b   = blockIdx.y;
    const float* __restrict__ xb = x + ((size_t)b * Cd << 18);

    if (tid < 64) rnk[tid] = rank[((size_t)b << 18) + p0 + tid];

    #pragma unroll
    for (int it = 0; it < 4; ++it) {
        const int c = it * 16 + (tid >> 4);
        const int j = tid & 15;
        floatx4 v = __builtin_nontemporal_load(
            (const floatx4*)(xb + ((size_t)c << 18) + p0 + 4 * j));
        lds[(4 * j + 0) * 65 + c] = v.x;
        lds[(4 * j + 1) * 65 + c] = v.y;
        lds[(4 * j + 2) * 65 + c] = v.z;
        lds[(4 * j + 3) * 65 + c] = v.w;
    }
    __syncthreads();

    unsigned* __restrict__ xb_t = xt + (((size_t)b << 18) << 5);   // b*HW*32
    #pragma unroll
    for (int it = 0; it < 8; ++it) {
        const int p  = it * 8 + (tid >> 5);
        const int cp = tid & 31;
        float lo = lds[p * 65 + 2 * cp];
        float hi = lds[p * 65 + 2 * cp + 1];
        unsigned packed = ((unsigned)f2bf(hi) << 16) | (unsigned)f2bf(lo);
        xb_t[((size_t)rnk[p] << 5) + cp] = packed;
    }
}

// ---------------------------------------------------------------------------
// 5) label sums: pure sequential stream over xt rows [start, start+n).
//    grid = (250, B), block = 256; wave w -> label bid*4+w.
//    Lane = (pixslot 0..7, q 0..7): uint4 per lane -> 8 pixels x 128B per
//    wave-load, fully coalesced. 3-step shfl reduce over pixslot.
// ---------------------------------------------------------------------------
__global__ __launch_bounds__(256)
void sum_kernel(const unsigned* __restrict__ xt, const int* __restrict__ cnt,
                const int* __restrict__ start, float* __restrict__ means) {
    const int tid  = threadIdx.x;
    const int b    = blockIdx.y;
    const int l    = blockIdx.x * 4 + (tid >> 6);
    const int lane = tid & 63;
    const int ps   = lane >> 3;     // pixel slot 0..7
    const int q    = lane & 7;      // uint4 slot within row (8 channels)

    int n = cnt[b * NLd + l];
    int s = start[b * NLd + l];
    if (s < 0) s = 0; if (s > HWp) s = HWp;
    if (n < 0) n = 0;
    if (n > HWp - s) n = HWp - s;

    const uint4* __restrict__ xb =
        (const uint4*)(xt + (((size_t)b << 18) << 5)) + ((size_t)s << 3) + q;

    float a0 = 0, a1 = 0, a2 = 0, a3 = 0, a4 = 0, a5 = 0, a6 = 0, a7 = 0;
    for (int pix = ps; pix < n; pix += 8) {
        uint4 u = xb[(size_t)pix << 3];
        a0 += bflo(u.x); a1 += bfhi(u.x);
        a2 += bflo(u.y); a3 += bfhi(u.y);
        a4 += bflo(u.z); a5 += bfhi(u.z);
        a6 += bflo(u.w); a7 += bfhi(u.w);
    }

    #pragma unroll
    for (int off = 8; off < 64; off <<= 1) {
        a0 += __shfl_xor(a0, off, 64);
        a1 += __shfl_xor(a1, off, 64);
        a2 += __shfl_xor(a2, off, 64);
        a3 += __shfl_xor(a3, off, 64);
        a4 += __shfl_xor(a4, off, 64);
        a5 += __shfl_xor(a5, off, 64);
        a6 += __shfl_xor(a6, off, 64);
        a7 += __shfl_xor(a7, off, 64);
    }

    if (ps == 0) {
        const float inv = 1.0f / (float)(n > 0 ? n : 1);
        float* dst = means + (((size_t)(b * NLd + l)) << 6) + q * 8;
        float4 o0; o0.x = a0 * inv; o0.y = a1 * inv; o0.z = a2 * inv; o0.w = a3 * inv;
        float4 o1; o1.x = a4 * inv; o1.y = a5 * inv; o1.z = a6 * inv; o1.w = a7 * inv;
        *(float4*)dst = o0;
        *(float4*)(dst + 4) = o1;
    }
}

__global__ __launch_bounds__(256)
void gather_kernel(const float* __restrict__ means,
                   const int* __restrict__ edges,
                   const float* __restrict__ ew,
                   float* __restrict__ out) {
    const int t  = blockIdx.x * 256 + threadIdx.x;   // 0 .. B*NS*C-1
    const int bs = t >> 6;                           // b*NS + s
    const int c  = t & 63;
    const int b  = bs >> 11;                         // NS = 2048

    const int la = clampl(edges[bs * 2 + 0]);
    const int lb = clampl(edges[bs * 2 + 1]);

    out[t] = means[((size_t)(b * NLd + la) << 6) + c];
    out[(size_t)Bd * NSd * Cd + t] = means[((size_t)(b * NLd + lb) << 6) + c];
    if (t < Bd * NSd)
        out[2 * (size_t)Bd * NSd * Cd + t] = ew[t];
}

// ===========================================================================
// FALLBACK PATH (R1 design, known-good 371 us; needs ~1 MB ws)
// ===========================================================================
#define WS_FB_ELEMS (Bd * Cd * NLd + Bd * NLd)

__global__ __launch_bounds__(256)
void fb_sums_kernel(const float* __restrict__ x, const int* __restrict__ lab,
                    float* __restrict__ sums) {
    __shared__ float lsum[NLd];
    const int tid   = threadIdx.x;
    const int chunk = blockIdx.x;
    const int c     = blockIdx.y;
    const int b     = blockIdx.z;

    for (int l = tid; l < NLd; l += 256) lsum[l] = 0.0f;
    __syncthreads();

    const float4* __restrict__ xp =
        (const float4*)x + (size_t)(b * Cd + c) * (HWp / 4);
    const int4* __restrict__ lp = (const int4*)lab + (size_t)b * (HWp / 4);

    const int nvec = HWp / 16;
    const int v0 = chunk * nvec, v1 = v0 + nvec;
    for (int v = v0 + tid; v < v1; v += 256) {
        float4 xv = xp[v];
        int4   lv = lp[v];
        atomicAdd(&lsum[clampl(lv.x)], xv.x);
        atomicAdd(&lsum[clampl(lv.y)], xv.y);
        atomicAdd(&lsum[clampl(lv.z)], xv.z);
        atomicAdd(&lsum[clampl(lv.w)], xv.w);
    }
    __syncthreads();

    float* __restrict__ dst = sums + (size_t)(b * Cd + c) * NLd;
    for (int l = tid; l < NLd; l += 256)
        atomicAdd(&dst[l], lsum[l]);
}

__global__ __launch_bounds__(256)
void fb_counts_kernel(const int* __restrict__ lab, float* __restrict__ counts) {
    __shared__ unsigned lcnt[NLd];
    const int tid   = threadIdx.x;
    const int chunk = blockIdx.x;
    const int b     = blockIdx.y;

    for (int l = tid; l < NLd; l += 256) lcnt[l] = 0u;
    __syncthreads();

    const int4* __restrict__ lp = (const int4*)lab + (size_t)b * (HWp / 4);
    const int nvec = HWp / 16;
    const int v0 = chunk * nvec, v1 = v0 + nvec;
    for (int v = v0 + tid; v < v1; v += 256) {
        int4 lv = lp[v];
        atomicAdd(&lcnt[clampl(lv.x)], 1u);
        atomicAdd(&lcnt[clampl(lv.y)], 1u);
        atomicAdd(&lcnt[clampl(lv.z)], 1u);
        atomicAdd(&lcnt[clampl(lv.w)], 1u);
    }
    __syncthreads();

    float* __restrict__ dst = counts + (size_t)b * NLd;
    for (int l = tid; l < NLd; l += 256)
        atomicAdd(&dst[l], (float)lcnt[l]);
}

__global__ __launch_bounds__(256)
void fb_gather_kernel(const float* __restrict__ sums,
                      const float* __restrict__ counts,
                      const int* __restrict__ edges,
                      const float* __restrict__ ew,
                      float* __restrict__ out) {
    const int t  = blockIdx.x * 256 + threadIdx.x;
    const int bs = t >> 6;
    const int c  = t & 63;
    const int b  = bs >> 11;

    const int la = clampl(edges[bs * 2 + 0]);
    const int lb = clampl(edges[bs * 2 + 1]);

    const float ca = fmaxf(counts[b * NLd + la], 1.0f);
    const float cb = fmaxf(counts[b * NLd + lb], 1.0f);

    const size_t plane = (size_t)(b * Cd + c) * NLd;
    out[t] = sums[plane + la] / ca;
    out[(size_t)Bd * NSd * Cd + t] = sums[plane + lb] / cb;
    if (t < Bd * NSd)
        out[2 * (size_t)Bd * NSd * Cd + t] = ew[t];
}

extern "C" void kernel_launch(void* const* d_in, const int* in_sizes, int n_in,
                              void* d_out, int out_size, void* d_ws, size_t ws_size,
                              hipStream_t stream) {
    const float* x     = (const float*)d_in[0];   // [B,C,H,W] f32
    const int*   lab   = (const int*)d_in[1];     // [B,1,H,W] i32
    const int*   edges = (const int*)d_in[2];     // [B,NS,2] i32
    const float* ew    = (const float*)d_in[3];   // [B,NS] f32
    float*       out   = (float*)d_out;

    const int n_gather = Bd * NSd * Cd;   // 524288

    if (ws_size >= (size_t)WS_ELEMS * sizeof(int)) {
        int*      wsi       = (int*)d_ws;
        int*      cnt       = wsi + OFF_CNT;
        int*      start     = wsi + OFF_START;
        int*      blockCnt  = wsi + OFF_BCNT;
        int*      blockBase = wsi + OFF_BBASE;
        int*      rank      = wsi + OFF_RANK;
        float*    means     = (float*)(wsi + OFF_MEANS);
        unsigned* xt        = (unsigned*)(wsi + OFF_XT);

        blockcnt_kernel<<<NBLK, 256, 0, stream>>>(lab, blockCnt);
        scan_kernel<<<Bd, 1024, 0, stream>>>(blockCnt, cnt, start, blockBase);
        rank_kernel<<<NBLK, 256, 0, stream>>>(lab, blockBase, rank);
        transpose_kernel<<<dim3(HWp / 64, Bd), 256, 0, stream>>>(x, rank, xt);
        sum_kernel<<<dim3(NLd / 4, Bd), 256, 0, stream>>>(xt, cnt, start, means);
        gather_kernel<<<n_gather / 256, 256, 0, stream>>>(means, edges, ew, out);
    } else {
        // ---- fallback: R1 atomic path ----
        float* sums   = (float*)d_ws;
        float* counts = sums + (size_t)Bd * Cd * NLd;

        hipMemsetAsync(d_ws, 0, (size_t)WS_FB_ELEMS * sizeof(float), stream);

        fb_sums_kernel<<<dim3(4, Cd, Bd), 256, 0, stream>>>(x, lab, sums);
        fb_counts_kernel<<<dim3(4, Bd), 256, 0, stream>>>(lab, counts);
        fb_gather_kernel<<<n_gather / 256, 256, 0, stream>>>(sums, counts, edges, ew, out);
    }
}